// Round 1
// 430.634 us; speedup vs baseline: 1.0331x; 1.0331x over previous
//
#include <hip/hip_runtime.h>
#include <math.h>

// Problem constants
#define BB 8
#define TT 8192
#define FF 1024
#define HH 256
#define MT 64               // rows per block
#define NBLK ((BB*TT)/MT)   // 1024 main blocks
#define PBAG (TT/MT)        // 128 blocks per bag
#define PSTR 260            // floats per partial record: [m, l, acc[256], pad2]

typedef __attribute__((ext_vector_type(8))) short bf16x8;
typedef __attribute__((ext_vector_type(4))) float f32x4;

__device__ __forceinline__ float b2f(unsigned short s) {
    union { unsigned u; float f; } v; v.u = ((unsigned)s) << 16; return v.f;
}
__device__ __forceinline__ unsigned short f2b(float f) {
    union { float f; unsigned u; } v; v.f = f;
    unsigned u = v.u;
    return (unsigned short)((u + 0x7fffu + ((u >> 16) & 1u)) >> 16);
}
__device__ __forceinline__ unsigned pk2(float a, float b) {
    return (unsigned)f2b(a) | ((unsigned)f2b(b) << 16);
}

// ---------------- prep: emit weights in MFMA B-fragment order ----------------
// W1f frag addr: (((w*16+kb)*2+k0i)*4+ni)*512 + lane*8 + j
//   holds W1[k][n], n = w*64+ni*16+(lane&15), k = kb*64+k0i*32+(lane>>4)*8+j
// Wvf/Wuf frag addr: ((w*4+nc)*8+ks)*512 + lane*8 + j
__global__ __launch_bounds__(256)
void mil_prep(const float* __restrict__ W1,
              const float* __restrict__ Wv,
              const float* __restrict__ Wu,
              unsigned short* __restrict__ W1f,
              unsigned short* __restrict__ Wvf,
              unsigned short* __restrict__ Wuf) {
    __shared__ unsigned short T[64 * 264];
    const int b = blockIdx.x;
    const int t = threadIdx.x;
    if (b < 64) {
        const int w = b >> 4, kb = b & 15;
#pragma unroll
        for (int i = 0; i < 4; ++i) {
            int f = t + i * 256;
            int r = f >> 4, c4 = (f & 15) * 4;
            float4 v = *(const float4*)(W1 + (size_t)(kb * 64 + r) * 256 + w * 64 + c4);
            T[(c4 + 0) * 72 + r] = f2b(v.x);
            T[(c4 + 1) * 72 + r] = f2b(v.y);
            T[(c4 + 2) * 72 + r] = f2b(v.z);
            T[(c4 + 3) * 72 + r] = f2b(v.w);
        }
        __syncthreads();
#pragma unroll
        for (int i = 0; i < 2; ++i) {
            int c = t + i * 256;
            int fl = c >> 6;
            int k0i = fl >> 2, ni = fl & 3;
            int lane = c & 63, l15 = lane & 15, q = lane >> 4;
            *(uint4*)(W1f + ((size_t)(w * 16 + kb) * 8 + fl) * 512 + lane * 8) =
                *(const uint4*)&T[(ni * 16 + l15) * 72 + k0i * 32 + q * 8];
        }
    } else {
        const int m = (b - 64) >> 2;
        const int w = (b - 64) & 3;
        const float* src = m ? Wu : Wv;
        unsigned short* dst = m ? Wuf : Wvf;
#pragma unroll
        for (int i = 0; i < 16; ++i) {
            int f = t + i * 256;
            int r = f >> 4, c4 = (f & 15) * 4;
            float4 v = *(const float4*)(src + (size_t)r * 256 + w * 64 + c4);
            T[(c4 + 0) * 264 + r] = f2b(v.x);
            T[(c4 + 1) * 264 + r] = f2b(v.y);
            T[(c4 + 2) * 264 + r] = f2b(v.z);
            T[(c4 + 3) * 264 + r] = f2b(v.w);
        }
        __syncthreads();
#pragma unroll
        for (int i = 0; i < 8; ++i) {
            int c = t + i * 256;
            int fl = c >> 6;
            int nc = fl >> 3, ks = fl & 7;
            int lane = c & 63, l15 = lane & 15, q = lane >> 4;
            *(uint4*)(dst + ((size_t)(w * 4 + nc) * 8 + ks) * 512 + lane * 8) =
                *(const uint4*)&T[(nc * 16 + l15) * 264 + ks * 32 + q * 8];
        }
    }
}

// ---------------- fused: h = relu(bags@W1+b1) -> gated attn -> block partials --
// Stage-1 half: BK=128 chunks (8 iters), LDS double-buffered (stride 136 = 2-way
// bank alias, free), B-frags issued before the bags prefetch so the MFMA vmcnt
// wait leaves pf in flight. After the K-loop, bias+ReLU writes Ht[64][264] into
// the SAME LDS; stage-2 half (gated attention MFMAs) consumes it directly — no
// Hg round trip (saves 67 MB HBM), no launch boundary. Co-resident blocks
// desync, overlapping one block's stage-2 MFMA with the other's stage-1 BW.
// 2 blocks/CU, ~200 VGPR peak (stage-2 regs reuse dead acc/bb), no spill.
__global__ __launch_bounds__(256, 2)
void mil_fused(const float* __restrict__ bags,
               const float* __restrict__ b1,
               const unsigned short* __restrict__ W1f,
               const unsigned char* __restrict__ mask,
               const float* __restrict__ bv,
               const float* __restrict__ bu,
               const float* __restrict__ ww,
               const float* __restrict__ bwp,
               const unsigned short* __restrict__ Wvf,
               const unsigned short* __restrict__ Wuf,
               float* __restrict__ P) {
    const int tid  = threadIdx.x;
    const int wave = tid >> 6;
    const int lane = tid & 63;
    const int l15  = lane & 15;
    const int quad = lane >> 4;
    const int blk  = blockIdx.x;
    const int bag  = blk >> 7;
    const int trow = (blk & 127) * MT;

    __shared__ unsigned short LB[2 * 64 * 136];   // 34816 B; Ht (64x264) aliases
    __shared__ float logits[MT];
    __shared__ float wrow[MT];
    __shared__ float sc[2];

    // ---------------- stage 1: h = relu(bags @ W1 + b1) -> Ht in LDS ---------
    f32x4 acc[4][4];
#pragma unroll
    for (int mi = 0; mi < 4; ++mi)
#pragma unroll
        for (int ni = 0; ni < 4; ++ni)
            acc[mi][ni] = (f32x4){0.f, 0.f, 0.f, 0.f};

    const float* bagrow = bags + (size_t)blk * MT * FF;
    int fr[8], fc[8];
    float4 pf[8];
#pragma unroll
    for (int i = 0; i < 8; ++i) {
        int f = tid + i * 256;
        fr[i] = f >> 5;
        fc[i] = (f & 31) * 4;
        pf[i] = *(const float4*)(bagrow + (size_t)fr[i] * FF + fc[i]);
    }
    const unsigned short* bs = W1f + (size_t)wave * 16 * 4096;

#pragma unroll 2
    for (int kb2 = 0; kb2 < 8; ++kb2) {
        unsigned short* A = LB + (kb2 & 1) * 8704;   // 64*136
        // store staged chunk (waits pf: issued one full iteration ago)
#pragma unroll
        for (int i = 0; i < 8; ++i)
            *(uint2*)&A[fr[i] * 136 + fc[i]] =
                make_uint2(pk2(pf[i].x, pf[i].y), pk2(pf[i].z, pf[i].w));
        __syncthreads();                              // nothing outstanding: free drain
        // B-frags for both 64-K halves (issue FIRST -> MFMA wait = vmcnt(8), pf alive)
        bf16x8 bb[16];
#pragma unroll
        for (int f16 = 0; f16 < 16; ++f16)
            bb[f16] = *(const bf16x8*)(bs + (size_t)(kb2 * 2 + (f16 >> 3)) * 4096
                                       + (f16 & 7) * 512 + lane * 8);
        // prefetch next 128-K chunk of bags (in flight across the MFMA section)
        if (kb2 < 7) {
#pragma unroll
            for (int i = 0; i < 8; ++i)
                pf[i] = *(const float4*)(bagrow + (size_t)fr[i] * FF + (kb2 + 1) * 128 + fc[i]);
        }
#pragma unroll
        for (int k0i = 0; k0i < 4; ++k0i) {
            bf16x8 afr[4];
#pragma unroll
            for (int mi = 0; mi < 4; ++mi)
                afr[mi] = *(const bf16x8*)&A[(mi * 16 + l15) * 136 + k0i * 32 + quad * 8];
#pragma unroll
            for (int mi = 0; mi < 4; ++mi)
#pragma unroll
                for (int ni = 0; ni < 4; ++ni)
                    acc[mi][ni] = __builtin_amdgcn_mfma_f32_16x16x32_bf16(afr[mi], bb[k0i * 4 + ni], acc[mi][ni], 0, 0, 0);
        }
    }
    __syncthreads();   // all A reads done; reuse LB as Ht[64][264]

    {
        float bbv[4];
#pragma unroll
        for (int ni = 0; ni < 4; ++ni) bbv[ni] = b1[wave * 64 + ni * 16 + l15];
#pragma unroll
        for (int mi = 0; mi < 4; ++mi)
#pragma unroll
            for (int ni = 0; ni < 4; ++ni) {
                int n = wave * 64 + ni * 16 + l15;
#pragma unroll
                for (int r = 0; r < 4; ++r) {
                    int m = mi * 16 + quad * 4 + r;
                    float h = fmaxf(acc[mi][ni][r] + bbv[ni], 0.f);
                    LB[m * 264 + n] = f2b(h);
                }
            }
    }
    if (tid < MT) logits[tid] = 0.f;
    __syncthreads();   // Ht published, logits zeroed

    // ---------------- stage 2: gated attention + block softmax partials ------
    float rsum[4][4];
#pragma unroll
    for (int mi = 0; mi < 4; ++mi)
#pragma unroll
        for (int r = 0; r < 4; ++r) rsum[mi][r] = 0.f;

#pragma unroll 1
    for (int nc = 0; nc < 4; ++nc) {
        const int n = wave * 64 + nc * 16 + l15;
        const unsigned short* vs = Wvf + ((size_t)(wave * 4 + nc) * 8) * 512;
        const unsigned short* us = Wuf + ((size_t)(wave * 4 + nc) * 8) * 512;
        f32x4 av[4], au[4];
#pragma unroll
        for (int mi = 0; mi < 4; ++mi) {
            av[mi] = (f32x4){0.f, 0.f, 0.f, 0.f};
            au[mi] = (f32x4){0.f, 0.f, 0.f, 0.f};
        }
#pragma unroll 2
        for (int ks = 0; ks < 8; ++ks) {
            bf16x8 bvf = *(const bf16x8*)(vs + ks * 512 + lane * 8);
            bf16x8 buf_ = *(const bf16x8*)(us + ks * 512 + lane * 8);
            bf16x8 afr[4];
#pragma unroll
            for (int mi = 0; mi < 4; ++mi)
                afr[mi] = *(const bf16x8*)&LB[(mi * 16 + l15) * 264 + ks * 32 + quad * 8];
#pragma unroll
            for (int mi = 0; mi < 4; ++mi) {
                av[mi] = __builtin_amdgcn_mfma_f32_16x16x32_bf16(afr[mi], bvf, av[mi], 0, 0, 0);
                au[mi] = __builtin_amdgcn_mfma_f32_16x16x32_bf16(afr[mi], buf_, au[mi], 0, 0, 0);
            }
        }
        const float bvn = bv[n], bun = bu[n], wn = ww[n];
#pragma unroll
        for (int mi = 0; mi < 4; ++mi)
#pragma unroll
            for (int r = 0; r < 4; ++r) {
                float xv = av[mi][r] + bvn;
                float xu = au[mi][r] + bun;
                float tv = 2.f * __frcp_rn(1.f + __expf(-2.f * xv)) - 1.f;
                float su = __frcp_rn(1.f + __expf(-xu));
                rsum[mi][r] += tv * su * wn;
            }
    }
#pragma unroll
    for (int mi = 0; mi < 4; ++mi)
#pragma unroll
        for (int r = 0; r < 4; ++r) {
            float s = rsum[mi][r];
            s += __shfl_xor(s, 1);
            s += __shfl_xor(s, 2);
            s += __shfl_xor(s, 4);
            s += __shfl_xor(s, 8);
            if (l15 == 0) atomicAdd(&logits[mi * 16 + quad * 4 + r], s);
        }
    __syncthreads();

    if (tid < MT) {
        float lg = logits[tid] + bwp[0];
        if (mask[bag * TT + trow + tid]) lg = -INFINITY;
        logits[tid] = lg;
    }
    __syncthreads();

    if (wave == 0) {
        float v = logits[lane];
        float mx = v;
#pragma unroll
        for (int off = 1; off < 64; off <<= 1) mx = fmaxf(mx, __shfl_xor(mx, off));
        float w = (mx == -INFINITY) ? 0.f : __expf(v - mx);
        wrow[lane] = w;
        float l = w;
#pragma unroll
        for (int off = 1; off < 64; off <<= 1) l += __shfl_xor(l, off);
        if (lane == 0) { sc[0] = mx; sc[1] = l; }
    }
    __syncthreads();

    float a = 0.f;
#pragma unroll 8
    for (int m = 0; m < MT; ++m)
        a += wrow[m] * b2f(LB[m * 264 + tid]);

    float* rec = P + (size_t)blk * PSTR;
    rec[2 + tid] = a;
    if (tid == 0) { rec[0] = sc[0]; rec[1] = sc[1]; }
}

// ---------------- final: per-bag reduction + classifier ----------------
__global__ void mil_final(const float* __restrict__ P,
                          const float* __restrict__ Wc,
                          const float* __restrict__ bc,
                          float* __restrict__ out) {
    const int bag = blockIdx.x;
    const int tid = threadIdx.x;
    __shared__ float marr[PBAG];
    __shared__ float earr[PBAG];
    __shared__ float red[4];
    __shared__ float wred[8];

    if (tid < PBAG) marr[tid] = P[(size_t)(bag * PBAG + tid) * PSTR + 0];
    __syncthreads();
    if (tid < PBAG) {
        float v = marr[tid];
#pragma unroll
        for (int off = 1; off < 64; off <<= 1) v = fmaxf(v, __shfl_xor(v, off));
        if ((tid & 63) == 0) red[tid >> 6] = v;
    }
    __syncthreads();
    const float M = fmaxf(red[0], red[1]);
    if (tid < PBAG) {
        float e = (marr[tid] == -INFINITY) ? 0.f : __expf(marr[tid] - M);
        earr[tid] = e;
        float le = P[(size_t)(bag * PBAG + tid) * PSTR + 1] * e;
#pragma unroll
        for (int off = 1; off < 64; off <<= 1) le += __shfl_xor(le, off);
        if ((tid & 63) == 0) red[2 + (tid >> 6)] = le;
    }
    __syncthreads();
    const float L = red[2] + red[3];

    float accv = 0.f;
#pragma unroll 4
    for (int i = 0; i < PBAG; ++i)
        accv += earr[i] * P[(size_t)(bag * PBAG + i) * PSTR + 2 + tid];
    const float sr = accv / L;

    float p0 = sr * Wc[tid * 2 + 0];
    float p1 = sr * Wc[tid * 2 + 1];
#pragma unroll
    for (int off = 1; off < 64; off <<= 1) {
        p0 += __shfl_xor(p0, off);
        p1 += __shfl_xor(p1, off);
    }
    if ((tid & 63) == 0) {
        wred[(tid >> 6) * 2 + 0] = p0;
        wred[(tid >> 6) * 2 + 1] = p1;
    }
    __syncthreads();
    if (tid == 0) {
        out[bag * 2 + 0] = wred[0] + wred[2] + wred[4] + wred[6] + bc[0];
        out[bag * 2 + 1] = wred[1] + wred[3] + wred[5] + wred[7] + bc[1];
    }
}

extern "C" void kernel_launch(void* const* d_in, const int* in_sizes, int n_in,
                              void* d_out, int out_size, void* d_ws, size_t ws_size,
                              hipStream_t stream) {
    const float*         bags = (const float*)d_in[0];
    const unsigned char* mask = (const unsigned char*)d_in[1];
    const float*         W1   = (const float*)d_in[2];
    const float*         b1   = (const float*)d_in[3];
    const float*         Wv   = (const float*)d_in[4];
    const float*         bv   = (const float*)d_in[5];
    const float*         Wu   = (const float*)d_in[6];
    const float*         bu   = (const float*)d_in[7];
    const float*         ww   = (const float*)d_in[8];
    const float*         bw   = (const float*)d_in[9];
    const float*         Wc   = (const float*)d_in[10];
    const float*         bc   = (const float*)d_in[11];
    float* out = (float*)d_out;

    char* ws = (char*)d_ws;
    unsigned short* W1f = (unsigned short*)(ws);                    // 524288 B
    unsigned short* Wvf = (unsigned short*)(ws + 524288);           // 131072 B
    unsigned short* Wuf = (unsigned short*)(ws + 655360);           // 131072 B
    float*          P   = (float*)(ws + 786432);                    // 1064960 B

    mil_prep<<<72, 256, 0, stream>>>(W1, Wv, Wu, W1f, Wvf, Wuf);
    mil_fused<<<NBLK, 256, 0, stream>>>(bags, b1, W1f, mask, bv, bu, ww, bw, Wvf, Wuf, P);
    mil_final<<<BB, 256, 0, stream>>>(P, Wc, bc, out);
}